// Round 1
// baseline (1270.293 us; speedup 1.0000x reference)
//
#include <hip/hip_runtime.h>
#include <hip/hip_bf16.h>

#define N_USERS   100000
#define EMBED_DIM 128
#define N_EDGES   640000

typedef __bf16 bf16x8 __attribute__((ext_vector_type(8)));
typedef float  f32x4  __attribute__((ext_vector_type(4)));

// ---- workspace layout (bytes) ----
// [0,            51,200,000)  agg  fp32 [100000][128]
// [51,200,000,   51,600,000)  deg  fp32 [100000]
// [51,600,000,   51,632,768)  W_l  bf16 [128][128]
// [51,632,768,   51,665,536)  W_r  bf16 [128][128]
#define AGG_FLOATS  12800000   // 100000*128
#define DEG_FLOATS  100000
#define ZERO_F4     3225000    // (AGG_FLOATS+DEG_FLOATS)/4

__device__ __forceinline__ unsigned short f2bf_rne(float f) {
    union { float f; unsigned u; } c; c.f = f;
    unsigned u = c.u + 0x7fffu + ((c.u >> 16) & 1u);
    return (unsigned short)(u >> 16);
}

// Zero agg+deg, convert W_l/W_r fp32 -> bf16.
__global__ __launch_bounds__(256) void k_init(const float* __restrict__ Wl,
                                              const float* __restrict__ Wr,
                                              float* __restrict__ ws_f,
                                              unsigned short* __restrict__ wlb,
                                              unsigned short* __restrict__ wrb) {
    int i = blockIdx.x * 256 + threadIdx.x;
    if (i < ZERO_F4) {
        f32x4 z = {0.f, 0.f, 0.f, 0.f};
        ((f32x4*)ws_f)[i] = z;
    }
    if (i < 4096) {  // 16384 floats per W matrix / 4
        float4 a = ((const float4*)Wl)[i];
        float4 b = ((const float4*)Wr)[i];
        int o = i * 4;
        wlb[o+0] = f2bf_rne(a.x); wlb[o+1] = f2bf_rne(a.y);
        wlb[o+2] = f2bf_rne(a.z); wlb[o+3] = f2bf_rne(a.w);
        wrb[o+0] = f2bf_rne(b.x); wrb[o+1] = f2bf_rne(b.y);
        wrb[o+2] = f2bf_rne(b.z); wrb[o+3] = f2bf_rne(b.w);
    }
}

// One edge per 32 threads; each thread does 4 dims (float4 gather + 4 atomics).
__global__ __launch_bounds__(256) void k_scatter(const float* __restrict__ emb,
                                                 const int* __restrict__ src,
                                                 const int* __restrict__ dst,
                                                 float* __restrict__ agg,
                                                 float* __restrict__ deg) {
    int idx = blockIdx.x * 256 + threadIdx.x;
    int e  = idx >> 5;
    int d4 = (idx & 31) << 2;
    if (e < N_EDGES) {
        int s = src[e];
        int t = dst[e];
        const float4 v = *(const float4*)(emb + (long long)s * EMBED_DIM + d4);
        float* p = agg + (long long)t * EMBED_DIM + d4;
        atomicAdd(p + 0, v.x);
        atomicAdd(p + 1, v.y);
        atomicAdd(p + 2, v.z);
        atomicAdd(p + 3, v.w);
        if (d4 == 0) atomicAdd(deg + t, 1.0f);
    }
}

// out[n][j] = sum_k (agg[n][k]/max(deg,1)) * Wl[j][k] + emb[n][k] * Wr[j][k]  + bl[j]
// Wave tile: 16 rows x 128 cols, K=128 via 4 x mfma_f32_16x16x32_bf16 per jtile.
__global__ __launch_bounds__(256) void k_matmul(const float* __restrict__ agg,
                                                const float* __restrict__ deg,
                                                const unsigned short* __restrict__ wlb,
                                                const unsigned short* __restrict__ wrb,
                                                const float* __restrict__ emb,
                                                const float* __restrict__ bl,
                                                float* __restrict__ out) {
    int wave = threadIdx.x >> 6;
    int lane = threadIdx.x & 63;
    int tile = blockIdx.x * 4 + wave;
    if (tile >= (N_USERS / 16)) return;   // 6250 tiles, N divisible by 16

    int quad = lane >> 4;      // 0..3
    int m    = lane & 15;      // A-row within tile / B-col within jtile
    int row0 = tile * 16;
    int node = row0 + m;

    float inv = 1.0f / fmaxf(deg[node], 1.0f);
    const float* arow = agg + (long long)node * EMBED_DIM;
    const float* erow = emb + (long long)node * EMBED_DIM;

    f32x4 acc[8];
#pragma unroll
    for (int j = 0; j < 8; j++) acc[j] = (f32x4){0.f, 0.f, 0.f, 0.f};

#pragma unroll
    for (int kt = 0; kt < 4; kt++) {
        int kb = kt * 32 + quad * 8;     // this lane's 8 contiguous k values
        bf16x8 af, ef;
#pragma unroll
        for (int j = 0; j < 8; j++) {
            af[j] = (__bf16)(arow[kb + j] * inv);
            ef[j] = (__bf16)(erow[kb + j]);
        }
#pragma unroll
        for (int jt = 0; jt < 8; jt++) {
            bf16x8 blf = *(const bf16x8*)((const __bf16*)wlb + (jt * 16 + m) * EMBED_DIM + kb);
            bf16x8 brf = *(const bf16x8*)((const __bf16*)wrb + (jt * 16 + m) * EMBED_DIM + kb);
            acc[jt] = __builtin_amdgcn_mfma_f32_16x16x32_bf16(af, blf, acc[jt], 0, 0, 0);
            acc[jt] = __builtin_amdgcn_mfma_f32_16x16x32_bf16(ef, brf, acc[jt], 0, 0, 0);
        }
    }

    // Epilogue: C/D layout col = lane&15, row = quad*4 + reg
#pragma unroll
    for (int jt = 0; jt < 8; jt++) {
        float b = bl[jt * 16 + m];
#pragma unroll
        for (int r = 0; r < 4; r++) {
            int orow = row0 + quad * 4 + r;
            out[(long long)orow * EMBED_DIM + jt * 16 + m] = acc[jt][r] + b;
        }
    }
}

extern "C" void kernel_launch(void* const* d_in, const int* in_sizes, int n_in,
                              void* d_out, int out_size, void* d_ws, size_t ws_size,
                              hipStream_t stream) {
    const float* emb = (const float*)d_in[0];
    const float* Wl  = (const float*)d_in[1];
    const float* bl  = (const float*)d_in[2];
    const float* Wr  = (const float*)d_in[3];
    const int*   src = (const int*)d_in[4];
    const int*   dst = (const int*)d_in[5];
    float* out = (float*)d_out;

    float* agg = (float*)d_ws;
    float* deg = agg + AGG_FLOATS;
    unsigned short* wlb = (unsigned short*)((char*)d_ws + (size_t)(AGG_FLOATS + DEG_FLOATS) * 4);
    unsigned short* wrb = wlb + EMBED_DIM * EMBED_DIM;

    // 1) zero agg/deg + convert weights to bf16
    k_init<<<(ZERO_F4 + 255) / 256, 256, 0, stream>>>(Wl, Wr, agg, wlb, wrb);
    // 2) edge scatter (gather emb[src], atomic-add into agg[dst], count deg)
    k_scatter<<<(N_EDGES * 32) / 256, 256, 0, stream>>>(emb, src, dst, agg, deg);
    // 3) fused mean + dual GEMM + bias via bf16 MFMA
    k_matmul<<<(N_USERS / 16 + 3) / 4, 256, 0, stream>>>(agg, deg, wlb, wrb, emb, bl, out);
}

// Round 2
// 279.553 us; speedup vs baseline: 4.5440x; 4.5440x over previous
//
#include <hip/hip_runtime.h>
#include <hip/hip_bf16.h>

#define N_USERS   100000
#define EMBED_DIM 128
#define N_EDGES   640000

typedef __bf16 bf16x8 __attribute__((ext_vector_type(8)));
typedef float  f32x4  __attribute__((ext_vector_type(4)));

// ---- workspace layout (bytes) ----
// [0,          25,600,000)  aggb   bf16 [100000][128]  (mean-aggregated, pre-divided)
// [25,600,000, 26,000,000)  counts int  [100000]
// [26,000,000, 26,400,000)  start  int  [100000]
// [26,400,000, 26,800,000)  cursor int  [100000]
// [26,800,000, 29,360,000)  perm   int  [640000]   (src ids grouped by dst)
// [29,360,000, 29,392,768)  wlb    bf16 [128][128]
// [29,392,768, 29,425,536)  wrb    bf16 [128][128]
// [29,425,536, 29,425,540)  total  int  [1]
#define OFF_COUNTS 25600000
#define OFF_START  26000000
#define OFF_CURSOR 26400000
#define OFF_PERM   26800000
#define OFF_WLB    29360000
#define OFF_WRB    29392768
#define OFF_TOTAL  29425536

__device__ __forceinline__ unsigned short f2bf_rne(float f) {
    union { float f; unsigned u; } c; c.f = f;
    unsigned u = c.u + 0x7fffu + ((c.u >> 16) & 1u);
    return (unsigned short)(u >> 16);
}

// Zero counts + total, convert W_l/W_r fp32 -> bf16.  grid: 98 blocks x 256
__global__ __launch_bounds__(256) void k_init(const float* __restrict__ Wl,
                                              const float* __restrict__ Wr,
                                              int* __restrict__ counts,
                                              int* __restrict__ total,
                                              unsigned short* __restrict__ wlb,
                                              unsigned short* __restrict__ wrb) {
    int i = blockIdx.x * 256 + threadIdx.x;
    if (i < 25000) {   // 100000 ints / 4
        int4 z = {0, 0, 0, 0};
        ((int4*)counts)[i] = z;
    }
    if (i == 25000) *total = 0;
    if (i < 4096) {    // 16384 floats per W matrix / 4
        float4 a = ((const float4*)Wl)[i];
        float4 b = ((const float4*)Wr)[i];
        int o = i * 4;
        wlb[o+0] = f2bf_rne(a.x); wlb[o+1] = f2bf_rne(a.y);
        wlb[o+2] = f2bf_rne(a.z); wlb[o+3] = f2bf_rne(a.w);
        wrb[o+0] = f2bf_rne(b.x); wrb[o+1] = f2bf_rne(b.y);
        wrb[o+2] = f2bf_rne(b.z); wrb[o+3] = f2bf_rne(b.w);
    }
}

// Histogram of dst.  grid: 2500 x 256
__global__ __launch_bounds__(256) void k_hist(const int* __restrict__ dst,
                                              int* __restrict__ counts) {
    int e = blockIdx.x * 256 + threadIdx.x;
    if (e < N_EDGES) atomicAdd(&counts[dst[e]], 1);
}

// Exclusive allocation: start[t]/cursor[t] = running offset of counts[t].
// Node regions land in arbitrary global order (block-alloc via one atomic per
// block) — order is irrelevant, only contiguity per node matters.
// Each thread handles 4 nodes (int4).  grid: 98 blocks x 256 (25088 >= 25000)
__global__ __launch_bounds__(256) void k_alloc(const int* __restrict__ counts,
                                               int* __restrict__ start,
                                               int* __restrict__ cursor,
                                               int* __restrict__ total) {
    int i    = blockIdx.x * 256 + threadIdx.x;
    int lane = threadIdx.x & 63;
    int wv   = threadIdx.x >> 6;
    int4 c4 = {0, 0, 0, 0};
    if (i < 25000) c4 = ((const int4*)counts)[i];
    int csum = c4.x + c4.y + c4.z + c4.w;
    // wave inclusive scan of csum
    int pre = csum;
#pragma unroll
    for (int d = 1; d < 64; d <<= 1) {
        int v = __shfl_up(pre, d);
        if (lane >= d) pre += v;
    }
    __shared__ int swv[4];
    __shared__ int sgbase;
    if (lane == 63) swv[wv] = pre;
    __syncthreads();
    if (threadIdx.x == 0)
        sgbase = atomicAdd(total, swv[0] + swv[1] + swv[2] + swv[3]);
    __syncthreads();
    int waveoff = 0;
    for (int w = 0; w < wv; w++) waveoff += swv[w];
    int base = sgbase + waveoff + (pre - csum);   // exclusive within wave
    if (i < 25000) {
        int4 s;
        s.x = base;
        s.y = s.x + c4.x;
        s.z = s.y + c4.y;
        s.w = s.z + c4.z;
        ((int4*)start)[i]  = s;
        ((int4*)cursor)[i] = s;
    }
}

// Scatter edge src-ids into dst-grouped buckets.  grid: 2500 x 256
__global__ __launch_bounds__(256) void k_perm(const int* __restrict__ src,
                                              const int* __restrict__ dst,
                                              int* __restrict__ cursor,
                                              int* __restrict__ perm) {
    int e = blockIdx.x * 256 + threadIdx.x;
    if (e < N_EDGES) {
        int pos = atomicAdd(&cursor[dst[e]], 1);
        perm[pos] = src[e];
    }
}

// Gather-side mean aggregation: one wave per node, fp32 accumulate,
// pre-divide by degree, store bf16.  grid: 25000 blocks x 256 (4 waves)
__global__ __launch_bounds__(256) void k_aggregate(const float* __restrict__ emb,
                                                   const int* __restrict__ start,
                                                   const int* __restrict__ counts,
                                                   const int* __restrict__ perm,
                                                   unsigned short* __restrict__ aggb) {
    int node = (blockIdx.x * 256 + threadIdx.x) >> 6;
    int lane = threadIdx.x & 63;
    if (node >= N_USERS) return;
    int s0  = start[node];
    int cnt = counts[node];
    float2 acc = {0.f, 0.f};
    int i = 0;
    for (; i + 1 < cnt; i += 2) {   // 2 rows in flight
        int sa = perm[s0 + i];
        int sb = perm[s0 + i + 1];
        float2 va = *(const float2*)(emb + (size_t)sa * EMBED_DIM + lane * 2);
        float2 vb = *(const float2*)(emb + (size_t)sb * EMBED_DIM + lane * 2);
        acc.x += va.x + vb.x;
        acc.y += va.y + vb.y;
    }
    if (i < cnt) {
        int sa = perm[s0 + i];
        float2 va = *(const float2*)(emb + (size_t)sa * EMBED_DIM + lane * 2);
        acc.x += va.x;
        acc.y += va.y;
    }
    float inv = (cnt > 0) ? 1.0f / (float)cnt : 0.0f;
    ushort2 o;
    o.x = f2bf_rne(acc.x * inv);
    o.y = f2bf_rne(acc.y * inv);
    *(ushort2*)(aggb + (size_t)node * EMBED_DIM + lane * 2) = o;
}

// out[n][j] = sum_k aggb[n][k]*Wl[j][k] + emb[n][k]*Wr[j][k] + bl[j]
// Wave tile: 16 rows x 128 cols, K=128 via 4 x mfma_f32_16x16x32_bf16 per jtile.
__global__ __launch_bounds__(256) void k_matmul(const unsigned short* __restrict__ aggb,
                                                const unsigned short* __restrict__ wlb,
                                                const unsigned short* __restrict__ wrb,
                                                const float* __restrict__ emb,
                                                const float* __restrict__ bl,
                                                float* __restrict__ out) {
    int wave = threadIdx.x >> 6;
    int lane = threadIdx.x & 63;
    int tile = blockIdx.x * 4 + wave;
    if (tile >= (N_USERS / 16)) return;   // 6250 tiles

    int quad = lane >> 4;      // 0..3
    int m    = lane & 15;
    int row0 = tile * 16;
    int node = row0 + m;

    const __bf16* arow = (const __bf16*)aggb + (size_t)node * EMBED_DIM;
    const float*  erow = emb + (size_t)node * EMBED_DIM;

    f32x4 acc[8];
#pragma unroll
    for (int j = 0; j < 8; j++) acc[j] = (f32x4){0.f, 0.f, 0.f, 0.f};

#pragma unroll
    for (int kt = 0; kt < 4; kt++) {
        int kb = kt * 32 + quad * 8;
        bf16x8 af = *(const bf16x8*)(arow + kb);
        bf16x8 ef;
#pragma unroll
        for (int j = 0; j < 8; j++) ef[j] = (__bf16)(erow[kb + j]);
#pragma unroll
        for (int jt = 0; jt < 8; jt++) {
            bf16x8 blf = *(const bf16x8*)((const __bf16*)wlb + (jt * 16 + m) * EMBED_DIM + kb);
            bf16x8 brf = *(const bf16x8*)((const __bf16*)wrb + (jt * 16 + m) * EMBED_DIM + kb);
            acc[jt] = __builtin_amdgcn_mfma_f32_16x16x32_bf16(af, blf, acc[jt], 0, 0, 0);
            acc[jt] = __builtin_amdgcn_mfma_f32_16x16x32_bf16(ef, brf, acc[jt], 0, 0, 0);
        }
    }

    // C/D layout: col = lane&15, row = quad*4 + reg
#pragma unroll
    for (int jt = 0; jt < 8; jt++) {
        float b = bl[jt * 16 + m];
#pragma unroll
        for (int r = 0; r < 4; r++) {
            int orow = row0 + quad * 4 + r;
            out[(size_t)orow * EMBED_DIM + jt * 16 + m] = acc[jt][r] + b;
        }
    }
}

extern "C" void kernel_launch(void* const* d_in, const int* in_sizes, int n_in,
                              void* d_out, int out_size, void* d_ws, size_t ws_size,
                              hipStream_t stream) {
    const float* emb = (const float*)d_in[0];
    const float* Wl  = (const float*)d_in[1];
    const float* bl  = (const float*)d_in[2];
    const float* Wr  = (const float*)d_in[3];
    const int*   src = (const int*)d_in[4];
    const int*   dst = (const int*)d_in[5];
    float* out = (float*)d_out;

    char* ws = (char*)d_ws;
    unsigned short* aggb   = (unsigned short*)ws;
    int*            counts = (int*)(ws + OFF_COUNTS);
    int*            start  = (int*)(ws + OFF_START);
    int*            cursor = (int*)(ws + OFF_CURSOR);
    int*            perm   = (int*)(ws + OFF_PERM);
    unsigned short* wlb    = (unsigned short*)(ws + OFF_WLB);
    unsigned short* wrb    = (unsigned short*)(ws + OFF_WRB);
    int*            total  = (int*)(ws + OFF_TOTAL);

    k_init<<<98, 256, 0, stream>>>(Wl, Wr, counts, total, wlb, wrb);
    k_hist<<<2500, 256, 0, stream>>>(dst, counts);
    k_alloc<<<98, 256, 0, stream>>>(counts, start, cursor, total);
    k_perm<<<2500, 256, 0, stream>>>(src, dst, cursor, perm);
    k_aggregate<<<25000, 256, 0, stream>>>(emb, start, counts, perm, aggb);
    k_matmul<<<(N_USERS / 16 + 3) / 4, 256, 0, stream>>>(aggb, wlb, wrb, emb, bl, out);
}

// Round 4
// 246.516 us; speedup vs baseline: 5.1530x; 1.1340x over previous
//
#include <hip/hip_runtime.h>
#include <hip/hip_bf16.h>

#define N_USERS   100000
#define EMBED_DIM 128
#define N_EDGES   640000

typedef __bf16 bf16x8 __attribute__((ext_vector_type(8)));
typedef float  f32x4  __attribute__((ext_vector_type(4)));

// ---- workspace layout (bytes) ----
// [0,          25,600,000)  embb   bf16 [100000][128]  (emb rounded to bf16)
// [25,600,000, 51,200,000)  aggb   bf16 [100000][128]  (mean-aggregated, pre-divided)
// [51,200,000, 51,600,000)  counts int  [100000]
// [51,600,000, 52,000,000)  start  int  [100000]
// [52,000,000, 52,400,000)  cursor int  [100000]
// [52,400,000, 54,960,000)  perm   int  [640000]   (src ids grouped by dst)
// [54,960,000, 54,992,768)  wlb    bf16 [128][128]
// [54,992,768, 55,025,536)  wrb    bf16 [128][128]
// [55,025,536, 55,025,540)  total  int  [1]
#define OFF_AGGB   25600000
#define OFF_COUNTS 51200000
#define OFF_START  51600000
#define OFF_CURSOR 52000000
#define OFF_PERM   52400000
#define OFF_WLB    54960000
#define OFF_WRB    54992768
#define OFF_TOTAL  55025536

__device__ __forceinline__ unsigned short f2bf_rne(float f) {
    union { float f; unsigned u; } c; c.f = f;
    unsigned u = c.u + 0x7fffu + ((c.u >> 16) & 1u);
    return (unsigned short)(u >> 16);
}
__device__ __forceinline__ float bf2f_lo(unsigned u) {
    union { float f; unsigned u; } c; c.u = u << 16;
    return c.f;
}
__device__ __forceinline__ float bf2f_hi(unsigned u) {
    union { float f; unsigned u; } c; c.u = u & 0xffff0000u;
    return c.f;
}

// Zero counts+total, convert W_l/W_r -> bf16, convert emb -> embb (bf16).
// grid: 6250 x 256 (1.6M threads x 8 floats = 12.8M = full emb table)
__global__ __launch_bounds__(256) void k_init(const float* __restrict__ emb,
                                              const float* __restrict__ Wl,
                                              const float* __restrict__ Wr,
                                              unsigned short* __restrict__ embb,
                                              int* __restrict__ counts,
                                              int* __restrict__ total,
                                              unsigned short* __restrict__ wlb,
                                              unsigned short* __restrict__ wrb) {
    int i = blockIdx.x * 256 + threadIdx.x;
    if (i < 25000) {   // 100000 ints / 4
        int4 z = {0, 0, 0, 0};
        ((int4*)counts)[i] = z;
    }
    if (i == 25000) *total = 0;
    if (i < 4096) {    // 16384 floats per W matrix / 4
        float4 a = ((const float4*)Wl)[i];
        float4 b = ((const float4*)Wr)[i];
        int o = i * 4;
        wlb[o+0] = f2bf_rne(a.x); wlb[o+1] = f2bf_rne(a.y);
        wlb[o+2] = f2bf_rne(a.z); wlb[o+3] = f2bf_rne(a.w);
        wrb[o+0] = f2bf_rne(b.x); wrb[o+1] = f2bf_rne(b.y);
        wrb[o+2] = f2bf_rne(b.z); wrb[o+3] = f2bf_rne(b.w);
    }
    // emb -> embb, 8 floats per thread
    float4 a = ((const float4*)emb)[i * 2 + 0];
    float4 b = ((const float4*)emb)[i * 2 + 1];
    int4 p;
    p.x = (int)f2bf_rne(a.x) | ((int)f2bf_rne(a.y) << 16);
    p.y = (int)f2bf_rne(a.z) | ((int)f2bf_rne(a.w) << 16);
    p.z = (int)f2bf_rne(b.x) | ((int)f2bf_rne(b.y) << 16);
    p.w = (int)f2bf_rne(b.z) | ((int)f2bf_rne(b.w) << 16);
    ((int4*)embb)[i] = p;
}

// Histogram of dst.  grid: 2500 x 256
__global__ __launch_bounds__(256) void k_hist(const int* __restrict__ dst,
                                              int* __restrict__ counts) {
    int e = blockIdx.x * 256 + threadIdx.x;
    if (e < N_EDGES) atomicAdd(&counts[dst[e]], 1);
}

// Exclusive allocation of contiguous per-node regions (order arbitrary).
// grid: 98 x 256
__global__ __launch_bounds__(256) void k_alloc(const int* __restrict__ counts,
                                               int* __restrict__ start,
                                               int* __restrict__ cursor,
                                               int* __restrict__ total) {
    int i    = blockIdx.x * 256 + threadIdx.x;
    int lane = threadIdx.x & 63;
    int wv   = threadIdx.x >> 6;
    int4 c4 = {0, 0, 0, 0};
    if (i < 25000) c4 = ((const int4*)counts)[i];
    int csum = c4.x + c4.y + c4.z + c4.w;
    int pre = csum;
#pragma unroll
    for (int d = 1; d < 64; d <<= 1) {
        int v = __shfl_up(pre, d);
        if (lane >= d) pre += v;
    }
    __shared__ int swv[4];
    __shared__ int sgbase;
    if (lane == 63) swv[wv] = pre;
    __syncthreads();
    if (threadIdx.x == 0)
        sgbase = atomicAdd(total, swv[0] + swv[1] + swv[2] + swv[3]);
    __syncthreads();
    int waveoff = 0;
    for (int w = 0; w < wv; w++) waveoff += swv[w];
    int base = sgbase + waveoff + (pre - csum);
    if (i < 25000) {
        int4 s;
        s.x = base;
        s.y = s.x + c4.x;
        s.z = s.y + c4.y;
        s.w = s.z + c4.z;
        ((int4*)start)[i]  = s;
        ((int4*)cursor)[i] = s;
    }
}

// Scatter edge src-ids into dst-grouped buckets.  grid: 2500 x 256
__global__ __launch_bounds__(256) void k_perm(const int* __restrict__ src,
                                              const int* __restrict__ dst,
                                              int* __restrict__ cursor,
                                              int* __restrict__ perm) {
    int e = blockIdx.x * 256 + threadIdx.x;
    if (e < N_EDGES) {
        int pos = atomicAdd(&cursor[dst[e]], 1);
        perm[pos] = src[e];
    }
}

// Gather-side mean aggregation over bf16 rows: one wave per node, 2 bf16
// (one dword) per lane (64 x 2 = 128), fp32 accumulate, pre-divide by
// degree, store bf16.  4 rows in flight.  grid: 25000 x 256
__global__ __launch_bounds__(256) void k_aggregate(const unsigned short* __restrict__ embb,
                                                   const int* __restrict__ start,
                                                   const int* __restrict__ counts,
                                                   const int* __restrict__ perm,
                                                   unsigned short* __restrict__ aggb) {
    int node = (blockIdx.x * 256 + threadIdx.x) >> 6;
    int lane = threadIdx.x & 63;
    if (node >= N_USERS) return;
    int s0  = start[node];
    int cnt = counts[node];
    float2 acc = {0.f, 0.f};
    int i = 0;
    for (; i + 3 < cnt; i += 4) {   // 4 rows in flight
        int sa = perm[s0 + i + 0];
        int sb = perm[s0 + i + 1];
        int sc = perm[s0 + i + 2];
        int sd = perm[s0 + i + 3];
        unsigned va = *(const unsigned*)(embb + (size_t)sa * EMBED_DIM + lane * 2);
        unsigned vb = *(const unsigned*)(embb + (size_t)sb * EMBED_DIM + lane * 2);
        unsigned vc = *(const unsigned*)(embb + (size_t)sc * EMBED_DIM + lane * 2);
        unsigned vd = *(const unsigned*)(embb + (size_t)sd * EMBED_DIM + lane * 2);
        acc.x += (bf2f_lo(va) + bf2f_lo(vb)) + (bf2f_lo(vc) + bf2f_lo(vd));
        acc.y += (bf2f_hi(va) + bf2f_hi(vb)) + (bf2f_hi(vc) + bf2f_hi(vd));
    }
    for (; i < cnt; i++) {
        int sa = perm[s0 + i];
        unsigned va = *(const unsigned*)(embb + (size_t)sa * EMBED_DIM + lane * 2);
        acc.x += bf2f_lo(va);
        acc.y += bf2f_hi(va);
    }
    float inv = (cnt > 0) ? 1.0f / (float)cnt : 0.0f;
    unsigned o = (unsigned)f2bf_rne(acc.x * inv) | ((unsigned)f2bf_rne(acc.y * inv) << 16);
    *(unsigned*)(aggb + (size_t)node * EMBED_DIM + lane * 2) = o;
}

// out[n][j] = sum_k aggb[n][k]*Wl[j][k] + embb[n][k]*Wr[j][k] + bl[j]
// Each wave owns 2 of 8 column-tiles with B-fragments register-resident,
// and iterates over 5 row-tiles.  grid: 1250 x 256 (4 waves x 2 jtiles = 8)
#define TILES_PER_BLOCK 5
__global__ __launch_bounds__(256, 4) void k_matmul(const unsigned short* __restrict__ aggb,
                                                   const unsigned short* __restrict__ wlb,
                                                   const unsigned short* __restrict__ wrb,
                                                   const unsigned short* __restrict__ embb,
                                                   const float* __restrict__ bl,
                                                   float* __restrict__ out) {
    int wave = threadIdx.x >> 6;
    int lane = threadIdx.x & 63;
    int quad = lane >> 4;      // 0..3
    int m    = lane & 15;
    int jt0  = wave * 2;       // this wave's two column tiles

    // Register-resident B fragments: B[n=m][k = kt*32 + quad*8 + j]
    bf16x8 wl[2][4], wr[2][4];
#pragma unroll
    for (int jj = 0; jj < 2; jj++) {
#pragma unroll
        for (int kt = 0; kt < 4; kt++) {
            size_t off = (size_t)((jt0 + jj) * 16 + m) * EMBED_DIM + kt * 32 + quad * 8;
            wl[jj][kt] = *(const bf16x8*)((const __bf16*)wlb + off);
            wr[jj][kt] = *(const bf16x8*)((const __bf16*)wrb + off);
        }
    }
    float bias[2];
    bias[0] = bl[(jt0 + 0) * 16 + m];
    bias[1] = bl[(jt0 + 1) * 16 + m];

    int tile0 = blockIdx.x * TILES_PER_BLOCK;
#pragma unroll
    for (int t = 0; t < TILES_PER_BLOCK; t++) {
        int row0 = (tile0 + t) * 16;
        int node = row0 + m;
        const __bf16* arow = (const __bf16*)aggb + (size_t)node * EMBED_DIM;
        const __bf16* erow = (const __bf16*)embb + (size_t)node * EMBED_DIM;

        bf16x8 af[4], ef[4];
#pragma unroll
        for (int kt = 0; kt < 4; kt++) {
            int kb = kt * 32 + quad * 8;
            af[kt] = *(const bf16x8*)(arow + kb);
            ef[kt] = *(const bf16x8*)(erow + kb);
        }

        f32x4 acc[2] = {{0.f,0.f,0.f,0.f}, {0.f,0.f,0.f,0.f}};
#pragma unroll
        for (int kt = 0; kt < 4; kt++) {
#pragma unroll
            for (int jj = 0; jj < 2; jj++) {
                acc[jj] = __builtin_amdgcn_mfma_f32_16x16x32_bf16(af[kt], wl[jj][kt], acc[jj], 0, 0, 0);
                acc[jj] = __builtin_amdgcn_mfma_f32_16x16x32_bf16(ef[kt], wr[jj][kt], acc[jj], 0, 0, 0);
            }
        }

        // C/D layout: col = lane&15, row = quad*4 + reg
#pragma unroll
        for (int jj = 0; jj < 2; jj++) {
#pragma unroll
            for (int r = 0; r < 4; r++) {
                int orow = row0 + quad * 4 + r;
                out[(size_t)orow * EMBED_DIM + (jt0 + jj) * 16 + m] = acc[jj][r] + bias[jj];
            }
        }
    }
}

extern "C" void kernel_launch(void* const* d_in, const int* in_sizes, int n_in,
                              void* d_out, int out_size, void* d_ws, size_t ws_size,
                              hipStream_t stream) {
    const float* emb = (const float*)d_in[0];
    const float* Wl  = (const float*)d_in[1];
    const float* bl  = (const float*)d_in[2];
    const float* Wr  = (const float*)d_in[3];
    const int*   src = (const int*)d_in[4];
    const int*   dst = (const int*)d_in[5];
    float* out = (float*)d_out;

    char* ws = (char*)d_ws;
    unsigned short* embb   = (unsigned short*)ws;
    unsigned short* aggb   = (unsigned short*)(ws + OFF_AGGB);
    int*            counts = (int*)(ws + OFF_COUNTS);
    int*            start  = (int*)(ws + OFF_START);
    int*            cursor = (int*)(ws + OFF_CURSOR);
    int*            perm   = (int*)(ws + OFF_PERM);
    unsigned short* wlb    = (unsigned short*)(ws + OFF_WLB);
    unsigned short* wrb    = (unsigned short*)(ws + OFF_WRB);
    int*            total  = (int*)(ws + OFF_TOTAL);

    k_init<<<6250, 256, 0, stream>>>(emb, Wl, Wr, embb, counts, total, wlb, wrb);
    k_hist<<<2500, 256, 0, stream>>>(dst, counts);
    k_alloc<<<98, 256, 0, stream>>>(counts, start, cursor, total);
    k_perm<<<2500, 256, 0, stream>>>(src, dst, cursor, perm);
    k_aggregate<<<25000, 256, 0, stream>>>(embb, start, counts, perm, aggb);
    k_matmul<<<1250, 256, 0, stream>>>(aggb, wlb, wrb, embb, bl, out);
}